// Round 1
// baseline (491.180 us; speedup 1.0000x reference)
//
#include <hip/hip_runtime.h>

// Net_55439437857087: per-pixel MLP  2 -> tanh(8) -> 4x shared tanh(8x8) -> sigmoid(3)
// N = 16,777,216 pixels. Inputs: x[N,2] f32, W_in[8,2], W_h[8,8], W_out[3,8].
// Output: [N,3] f32.
//
// Design (R0): 4 pixels/thread so all HBM traffic is float4-coalesced.
// Weights are read with uniform constant indices -> scalar loads; the 8x8
// inner products become v_fma_f32 with the weight in the SGPR slot.
// tanh/sigmoid via v_exp_f32 + v_rcp_f32 (saturates correctly at +/-inf).

__device__ __forceinline__ float fast_tanh(float v) {
    // tanh(v) = 1 - 2/(exp(2v)+1); exp overflow -> rcp(inf)=0 -> +1, underflow -> -1
    float e = __expf(2.0f * v);
    return __builtin_fmaf(-2.0f, __builtin_amdgcn_rcpf(e + 1.0f), 1.0f);
}

__device__ __forceinline__ float fast_sigmoid(float v) {
    return __builtin_amdgcn_rcpf(1.0f + __expf(-v));
}

__global__ __launch_bounds__(256) void net_mlp_kernel(
    const float* __restrict__ x,
    const float* __restrict__ Win,   // [8,2]
    const float* __restrict__ Wh,    // [8,8]
    const float* __restrict__ Wout,  // [3,8]
    float* __restrict__ out,         // [N,3]
    int npix)
{
    const int t = blockIdx.x * blockDim.x + threadIdx.x;
    if (t * 4 >= npix) return;

    // ---- weights: uniform loads (compiler -> s_load), live in s/v regs ----
    float win[16], wh[64], wout[24];
#pragma unroll
    for (int i = 0; i < 16; ++i) win[i] = Win[i];
#pragma unroll
    for (int i = 0; i < 64; ++i) wh[i] = Wh[i];
#pragma unroll
    for (int i = 0; i < 24; ++i) wout[i] = Wout[i];

    // ---- load 4 pixels = 8 floats as two float4 ----
    const float4* xv = reinterpret_cast<const float4*>(x);
    float4 xa = xv[2 * t + 0];
    float4 xb = xv[2 * t + 1];
    float px[4][2] = {{xa.x, xa.y}, {xa.z, xa.w}, {xb.x, xb.y}, {xb.z, xb.w}};

    // ---- input layer: h = tanh(x @ Win^T) ----
    float h[4][8];
#pragma unroll
    for (int p = 0; p < 4; ++p) {
#pragma unroll
        for (int j = 0; j < 8; ++j) {
            float acc = __builtin_fmaf(px[p][0], win[2 * j],
                        px[p][1] * win[2 * j + 1]);
            h[p][j] = fast_tanh(acc);
        }
    }

    // ---- 4 shared hidden layers: h = tanh(h @ Wh^T) ----
#pragma unroll
    for (int L = 0; L < 4; ++L) {
        float nh[4][8];
#pragma unroll
        for (int p = 0; p < 4; ++p) {
#pragma unroll
            for (int j = 0; j < 8; ++j) {
                float acc = 0.0f;
#pragma unroll
                for (int k = 0; k < 8; ++k)
                    acc = __builtin_fmaf(h[p][k], wh[8 * j + k], acc);
                nh[p][j] = fast_tanh(acc);
            }
        }
#pragma unroll
        for (int p = 0; p < 4; ++p)
#pragma unroll
            for (int j = 0; j < 8; ++j) h[p][j] = nh[p][j];
    }

    // ---- output layer: sigmoid(h @ Wout^T) ----
    float o[4][3];
#pragma unroll
    for (int p = 0; p < 4; ++p) {
#pragma unroll
        for (int c = 0; c < 3; ++c) {
            float acc = 0.0f;
#pragma unroll
            for (int k = 0; k < 8; ++k)
                acc = __builtin_fmaf(h[p][k], wout[8 * c + k], acc);
            o[p][c] = fast_sigmoid(acc);
        }
    }

    // ---- store 12 floats as three float4 (48 B contiguous per thread) ----
    float4 s0 = make_float4(o[0][0], o[0][1], o[0][2], o[1][0]);
    float4 s1 = make_float4(o[1][1], o[1][2], o[2][0], o[2][1]);
    float4 s2 = make_float4(o[2][2], o[3][0], o[3][1], o[3][2]);
    float4* op = reinterpret_cast<float4*>(out);
    op[3 * t + 0] = s0;
    op[3 * t + 1] = s1;
    op[3 * t + 2] = s2;
}

extern "C" void kernel_launch(void* const* d_in, const int* in_sizes, int n_in,
                              void* d_out, int out_size, void* d_ws, size_t ws_size,
                              hipStream_t stream) {
    const float* x    = (const float*)d_in[0];
    const float* Win  = (const float*)d_in[1];
    const float* Wh   = (const float*)d_in[2];
    const float* Wout = (const float*)d_in[3];
    float* out = (float*)d_out;

    const int npix = in_sizes[0] / 2;        // 16,777,216
    const int nthreads = npix / 4;           // 4 pixels per thread
    const int block = 256;
    const int grid = (nthreads + block - 1) / block;

    net_mlp_kernel<<<grid, block, 0, stream>>>(x, Win, Wh, Wout, out, npix);
}

// Round 2
// 460.059 us; speedup vs baseline: 1.0676x; 1.0676x over previous
//
#include <hip/hip_runtime.h>

// Net_55439437857087: per-pixel MLP  2 -> tanh(8) -> 4x shared tanh(8x8) -> sigmoid(3)
// N = 16,777,216 pixels. Compute-bound on VALU issue (R1: VALUBusy 94%, HBM 8%).
//
// R2 changes:
//  - prep kernel folds 2*log2(e) into W_in/W_h rows and -log2(e) into W_out,
//    so every activation is exactly: exp2(u) -> +1 -> rcp -> fma  (raw
//    v_exp_f32 / v_rcp_f32, no OCML range-reduction bloat, no per-activation
//    scale muls).
//  - tanh(acc) = 1 - 2*rcp(exp2(2*log2e*acc) + 1)   (saturates correctly)
//    sigmoid(acc) = rcp(1 + exp2(-log2e*acc))

#if __has_builtin(__builtin_amdgcn_exp2f)
#define EXP2F(x) __builtin_amdgcn_exp2f(x)
#else
extern "C" __device__ float __ocml_native_exp2_f32(float);
#define EXP2F(x) __ocml_native_exp2_f32(x)
#endif
#define RCPF(x) __builtin_amdgcn_rcpf(x)

// d_ws layout: [0..15] W_in*2log2e, [16..79] W_h*2log2e, [80..103] W_out*(-log2e)
__global__ void prep_weights_kernel(const float* __restrict__ Win,
                                    const float* __restrict__ Wh,
                                    const float* __restrict__ Wout,
                                    float* __restrict__ w) {
    const float S  = 2.8853900817779268f;   // 2*log2(e)
    const float SO = -1.4426950408889634f;  // -log2(e)
    int i = threadIdx.x;
    if (i < 16)       w[i] = Win[i] * S;
    else if (i < 80)  w[i] = Wh[i - 16] * S;
    else if (i < 104) w[i] = Wout[i - 80] * SO;
}

__device__ __forceinline__ float tanh_from_u(float u) {
    // u = 2*log2e*acc ; tanh(acc) = 1 - 2/(exp2(u)+1)
    return __builtin_fmaf(-2.0f, RCPF(EXP2F(u) + 1.0f), 1.0f);
}

__device__ __forceinline__ float sigmoid_from_u(float u) {
    // u = -log2e*acc ; sigmoid(acc) = 1/(1+exp2(u))
    return RCPF(EXP2F(u) + 1.0f);
}

__global__ __launch_bounds__(256) void net_mlp_kernel(
    const float* __restrict__ x,
    const float* __restrict__ w,     // prepped weights in d_ws
    float* __restrict__ out,         // [N,3]
    int npix)
{
    const int t = blockIdx.x * blockDim.x + threadIdx.x;
    if (t * 4 >= npix) return;

    // ---- weights: uniform indices -> scalar loads ----
    float win[16], wh[64], wout[24];
#pragma unroll
    for (int i = 0; i < 16; ++i) win[i] = w[i];
#pragma unroll
    for (int i = 0; i < 64; ++i) wh[i] = w[16 + i];
#pragma unroll
    for (int i = 0; i < 24; ++i) wout[i] = w[80 + i];

    // ---- load 4 pixels = 8 floats as two float4 ----
    const float4* xv = reinterpret_cast<const float4*>(x);
    float4 xa = xv[2 * t + 0];
    float4 xb = xv[2 * t + 1];
    float px[4][2] = {{xa.x, xa.y}, {xa.z, xa.w}, {xb.x, xb.y}, {xb.z, xb.w}};

    // ---- input layer ----
    float h[4][8];
#pragma unroll
    for (int p = 0; p < 4; ++p) {
#pragma unroll
        for (int j = 0; j < 8; ++j) {
            float u = __builtin_fmaf(px[p][0], win[2 * j],
                      px[p][1] * win[2 * j + 1]);
            h[p][j] = tanh_from_u(u);
        }
    }

    // ---- 4 shared hidden layers ----
#pragma unroll
    for (int L = 0; L < 4; ++L) {
        float nh[4][8];
#pragma unroll
        for (int p = 0; p < 4; ++p) {
#pragma unroll
            for (int j = 0; j < 8; ++j) {
                float acc = 0.0f;
#pragma unroll
                for (int k = 0; k < 8; ++k)
                    acc = __builtin_fmaf(h[p][k], wh[8 * j + k], acc);
                nh[p][j] = tanh_from_u(acc);
            }
        }
#pragma unroll
        for (int p = 0; p < 4; ++p)
#pragma unroll
            for (int j = 0; j < 8; ++j) h[p][j] = nh[p][j];
    }

    // ---- output layer ----
    float o[4][3];
#pragma unroll
    for (int p = 0; p < 4; ++p) {
#pragma unroll
        for (int c = 0; c < 3; ++c) {
            float acc = 0.0f;
#pragma unroll
            for (int k = 0; k < 8; ++k)
                acc = __builtin_fmaf(h[p][k], wout[8 * c + k], acc);
            o[p][c] = sigmoid_from_u(acc);
        }
    }

    // ---- store 12 floats as three float4 ----
    float4 s0 = make_float4(o[0][0], o[0][1], o[0][2], o[1][0]);
    float4 s1 = make_float4(o[1][1], o[1][2], o[2][0], o[2][1]);
    float4 s2 = make_float4(o[2][2], o[3][0], o[3][1], o[3][2]);
    float4* op = reinterpret_cast<float4*>(out);
    op[3 * t + 0] = s0;
    op[3 * t + 1] = s1;
    op[3 * t + 2] = s2;
}

extern "C" void kernel_launch(void* const* d_in, const int* in_sizes, int n_in,
                              void* d_out, int out_size, void* d_ws, size_t ws_size,
                              hipStream_t stream) {
    const float* x    = (const float*)d_in[0];
    const float* Win  = (const float*)d_in[1];
    const float* Wh   = (const float*)d_in[2];
    const float* Wout = (const float*)d_in[3];
    float* out = (float*)d_out;
    float* w   = (float*)d_ws;

    const int npix = in_sizes[0] / 2;        // 16,777,216
    const int nthreads = npix / 4;           // 4 pixels per thread
    const int block = 256;
    const int grid = (nthreads + block - 1) / block;

    prep_weights_kernel<<<1, 128, 0, stream>>>(Win, Wh, Wout, w);
    net_mlp_kernel<<<grid, block, 0, stream>>>(x, w, out, npix);
}

// Round 4
// 429.986 us; speedup vs baseline: 1.1423x; 1.0699x over previous
//
#include <hip/hip_runtime.h>
#include <hip/hip_fp16.h>

// Net_55439437857087: per-pixel MLP 2->8->4x(8x8)->3 over 16.7M pixels.
// R3/R4: the net is a smooth function of (x,y) in [0,1)^2 only -> tabulate on
// a 512x512 grid (fp16 RGB, 2 MB, L2-resident per XCD) and bilinear-interp.
// Direct evaluation (R2) measured 1173 lane-cycles/pixel, ~65% of it on
// v_exp/v_rcp (~9 slots each on gfx950). LUT kernel is ~45 VALU ops/pixel and
// memory-bound instead. x/out use nontemporal accesses to keep L2 for the table.

#define EXP2F(x) __builtin_amdgcn_exp2f(x)
#define RCPF(x)  __builtin_amdgcn_rcpf(x)

#define G 512
#define GM1F 511.0f

typedef float vfloat4 __attribute__((ext_vector_type(4)));  // nontemporal-compatible

// ---- shared network evaluation (scale constants folded inline) ----
__device__ __forceinline__ void net_eval(
    float px, float py,
    const float* __restrict__ Win, const float* __restrict__ Wh,
    const float* __restrict__ Wout, float o[3])
{
    const float S  = 2.8853900817779268f;   // 2*log2(e)
    const float SO = -1.4426950408889634f;  // -log2(e)
    float h[8];
#pragma unroll
    for (int j = 0; j < 8; ++j) {
        float acc = __builtin_fmaf(px, Win[2 * j], py * Win[2 * j + 1]);
        h[j] = __builtin_fmaf(-2.0f, RCPF(EXP2F(S * acc) + 1.0f), 1.0f);
    }
#pragma unroll
    for (int L = 0; L < 4; ++L) {
        float nh[8];
#pragma unroll
        for (int j = 0; j < 8; ++j) {
            float acc = 0.0f;
#pragma unroll
            for (int k = 0; k < 8; ++k)
                acc = __builtin_fmaf(h[k], Wh[8 * j + k], acc);
            nh[j] = __builtin_fmaf(-2.0f, RCPF(EXP2F(S * acc) + 1.0f), 1.0f);
        }
#pragma unroll
        for (int j = 0; j < 8; ++j) h[j] = nh[j];
    }
#pragma unroll
    for (int c = 0; c < 3; ++c) {
        float acc = 0.0f;
#pragma unroll
        for (int k = 0; k < 8; ++k)
            acc = __builtin_fmaf(h[k], Wout[8 * c + k], acc);
        o[c] = RCPF(EXP2F(SO * acc) + 1.0f);
    }
}

// ---- build the 512x512 fp16 RGB table in d_ws ----
__global__ __launch_bounds__(256) void build_lut_kernel(
    const float* __restrict__ Win, const float* __restrict__ Wh,
    const float* __restrict__ Wout, uint2* __restrict__ tab)
{
    int t = blockIdx.x * blockDim.x + threadIdx.x;
    if (t >= G * G) return;
    int i = t & (G - 1);
    int j = t >> 9;               // t / G
    const float inv = 1.0f / GM1F;
    float o[3];
    net_eval(i * inv, j * inv, Win, Wh, Wout, o);
    __half2 rg = __floats2half2_rn(o[0], o[1]);
    __half2 bz = __floats2half2_rn(o[2], 0.0f);
    uint2 v;
    v.x = *(unsigned int*)&rg;
    v.y = *(unsigned int*)&bz;
    tab[t] = v;
}

__device__ __forceinline__ float3 unpack_tex(uint2 v) {
    __half2 h01 = *(__half2*)&v.x;
    __half  h2  = *(__half*)&v.y;
    float2 rg = __half22float2(h01);
    return make_float3(rg.x, rg.y, __half2float(h2));
}

__device__ __forceinline__ float3 lerp3(float3 a, float3 b, float t) {
    return make_float3(__builtin_fmaf(t, b.x - a.x, a.x),
                       __builtin_fmaf(t, b.y - a.y, a.y),
                       __builtin_fmaf(t, b.z - a.z, a.z));
}

__device__ __forceinline__ float3 sample_bilinear(
    const uint2* __restrict__ tab, float px, float py)
{
    float fx = px * GM1F;
    float fy = py * GM1F;
    int ix = (int)fx;
    int iy = (int)fy;
    float tx = fx - (float)ix;
    float ty = fy - (float)iy;
    const uint2* r0 = tab + iy * G + ix;
    uint2 a = r0[0], b = r0[1];
    uint2 c = r0[G], d = r0[G + 1];
    float3 c0 = lerp3(unpack_tex(a), unpack_tex(b), tx);
    float3 c1 = lerp3(unpack_tex(c), unpack_tex(d), tx);
    return lerp3(c0, c1, ty);
}

// ---- main pass: 4 pixels/thread, NT loads/stores, L2-resident gathers ----
__global__ __launch_bounds__(256) void lut_main_kernel(
    const float* __restrict__ x, const uint2* __restrict__ tab,
    float* __restrict__ out, int npix)
{
    int t = blockIdx.x * blockDim.x + threadIdx.x;
    if (t * 4 >= npix) return;

    const vfloat4* xv = reinterpret_cast<const vfloat4*>(x);
    vfloat4 xa = __builtin_nontemporal_load(&xv[2 * t + 0]);
    vfloat4 xb = __builtin_nontemporal_load(&xv[2 * t + 1]);

    float3 o0 = sample_bilinear(tab, xa.x, xa.y);
    float3 o1 = sample_bilinear(tab, xa.z, xa.w);
    float3 o2 = sample_bilinear(tab, xb.x, xb.y);
    float3 o3 = sample_bilinear(tab, xb.z, xb.w);

    vfloat4 s0 = {o0.x, o0.y, o0.z, o1.x};
    vfloat4 s1 = {o1.y, o1.z, o2.x, o2.y};
    vfloat4 s2 = {o2.z, o3.x, o3.y, o3.z};
    vfloat4* op = reinterpret_cast<vfloat4*>(out);
    __builtin_nontemporal_store(s0, &op[3 * t + 0]);
    __builtin_nontemporal_store(s1, &op[3 * t + 1]);
    __builtin_nontemporal_store(s2, &op[3 * t + 2]);
}

// ---- fallback: direct evaluation (R2-equivalent), if ws too small ----
__global__ __launch_bounds__(256) void direct_kernel(
    const float* __restrict__ x,
    const float* __restrict__ Win, const float* __restrict__ Wh,
    const float* __restrict__ Wout, float* __restrict__ out, int npix)
{
    int t = blockIdx.x * blockDim.x + threadIdx.x;
    if (t * 4 >= npix) return;
    const float4* xv = reinterpret_cast<const float4*>(x);
    float4 xa = xv[2 * t + 0];
    float4 xb = xv[2 * t + 1];
    float o[4][3];
    net_eval(xa.x, xa.y, Win, Wh, Wout, o[0]);
    net_eval(xa.z, xa.w, Win, Wh, Wout, o[1]);
    net_eval(xb.x, xb.y, Win, Wh, Wout, o[2]);
    net_eval(xb.z, xb.w, Win, Wh, Wout, o[3]);
    float4 s0 = make_float4(o[0][0], o[0][1], o[0][2], o[1][0]);
    float4 s1 = make_float4(o[1][1], o[1][2], o[2][0], o[2][1]);
    float4 s2 = make_float4(o[2][2], o[3][0], o[3][1], o[3][2]);
    float4* op = reinterpret_cast<float4*>(out);
    op[3 * t + 0] = s0;
    op[3 * t + 1] = s1;
    op[3 * t + 2] = s2;
}

extern "C" void kernel_launch(void* const* d_in, const int* in_sizes, int n_in,
                              void* d_out, int out_size, void* d_ws, size_t ws_size,
                              hipStream_t stream) {
    const float* x    = (const float*)d_in[0];
    const float* Win  = (const float*)d_in[1];
    const float* Wh   = (const float*)d_in[2];
    const float* Wout = (const float*)d_in[3];
    float* out = (float*)d_out;

    const int npix = in_sizes[0] / 2;        // 16,777,216
    const int nthreads = npix / 4;
    const int block = 256;
    const int grid = (nthreads + block - 1) / block;

    const size_t lut_bytes = (size_t)G * G * sizeof(uint2);  // 2 MiB
    if (ws_size >= lut_bytes) {
        uint2* tab = (uint2*)d_ws;
        build_lut_kernel<<<(G * G) / block, block, 0, stream>>>(Win, Wh, Wout, tab);
        lut_main_kernel<<<grid, block, 0, stream>>>(x, tab, out, npix);
    } else {
        direct_kernel<<<grid, block, 0, stream>>>(x, Win, Wh, Wout, out, npix);
    }
}